// Round 9
// baseline (2982.586 us; speedup 1.0000x reference)
//
#include <hip/hip_runtime.h>
#include <math.h>

// DGCNN_Reg: B=8, N=4096, k=20.
// Point-major layouts: X[p][c], U[p][o], T[p][o] with p = b*4096 + n.
// Edge conv factorized: y[o,n,k] = U[idx[n,k]][o] + T[n][o];
// BN+LeakyReLU (scale>0) commutes with max over k.
// R9: sqnorm fused into gather (layers 2-4); topk extraction via value-only
// butterfly + ballot (was (v,idx) butterfly); 4-chain ILP scans; pd_sym
// reg-staged prefetch (no LDS doubling -- R7 showed dbuf costs occupancy).

constexpr int NPT = 4096;
constexpr int BATCH = 8;
constexpr int PTS = BATCH * NPT;   // 32768
constexpr float EPS = 1e-5f;
#define KC 16
#define PAD 68    // 64-wide tiles: 68 mod 32 = 4 -> conflict-free staging
#define PADB 132  // 128-wide tiles: 132 mod 32 = 4 -> conflict-free staging
#define NEG_INF -3.4e38f

// ---------------- sum of squares per point (layer-1 input only) ----------------
__global__ __launch_bounds__(256) void sqnorm(const float* __restrict__ X,
                                              float* __restrict__ xx, int C) {
    int p = blockIdx.x * 256 + threadIdx.x;
    if (p >= PTS) return;
    float s = 0.f;
    const float* row = X + (size_t)p * C;
    for (int c = 0; c < C; ++c) s = fmaf(row[c], row[c], s);
    xx[p] = s;
}

// ---------------- symmetric pairwise distances, 128x128 tiles, upper triangle ----
// Single-buffer LDS + register prefetch of next K-tile. pd bit-symmetric ->
// compute ti<=tj (528 of 1024 tiles), mirror store.
__global__ __launch_bounds__(256) void pd_sym128(const float* __restrict__ X,
                                                 const float* __restrict__ xx,
                                                 float* __restrict__ pd,
                                                 int C, int b) {
    int bid = blockIdx.x;
    int ti = 0, rem = bid;
    while (rem >= 32 - ti) { rem -= 32 - ti; ++ti; }
    int tj = ti + rem;
    int rowbase = ti * 128, colbase = tj * 128;

    __shared__ __align__(16) float As[KC][PADB];
    __shared__ __align__(16) float Bs[KC][PADB];
    int tid = threadIdx.x;
    int tx = tid & 15;          // col group
    int ty = tid >> 4;          // row group
    int p0 = b * NPT;
    int sc4 = (tid & 3) * 4;    // staging channel (float4)
    int spt = tid >> 2;         // staging point 0..63
    float acc[2][2][4][4] = {}; // [rh][ch][i][j]: row 64rh+4ty+i, col 64ch+4tx+j

    float4 pav[2], pbv[2];
#pragma unroll
    for (int h = 0; h < 2; ++h) {
        int pt = spt + h * 64;
        pav[h] = *(const float4*)&X[(size_t)(p0 + rowbase + pt) * C + sc4];
        pbv[h] = *(const float4*)&X[(size_t)(p0 + colbase + pt) * C + sc4];
    }
    for (int c0 = 0; c0 < C; c0 += KC) {
#pragma unroll
        for (int h = 0; h < 2; ++h) {
            int pt = spt + h * 64;
            As[sc4 + 0][pt] = pav[h].x; As[sc4 + 1][pt] = pav[h].y;
            As[sc4 + 2][pt] = pav[h].z; As[sc4 + 3][pt] = pav[h].w;
            Bs[sc4 + 0][pt] = pbv[h].x; Bs[sc4 + 1][pt] = pbv[h].y;
            Bs[sc4 + 2][pt] = pbv[h].z; Bs[sc4 + 3][pt] = pbv[h].w;
        }
        __syncthreads();
        if (c0 + KC < C) {
#pragma unroll
            for (int h = 0; h < 2; ++h) {
                int pt = spt + h * 64;
                pav[h] = *(const float4*)&X[(size_t)(p0 + rowbase + pt) * C + c0 + KC + sc4];
                pbv[h] = *(const float4*)&X[(size_t)(p0 + colbase + pt) * C + c0 + KC + sc4];
            }
        }
#pragma unroll
        for (int cc = 0; cc < KC; ++cc) {
            float4 a0 = *(const float4*)&As[cc][ty * 4];
            float4 a1 = *(const float4*)&As[cc][64 + ty * 4];
            float4 b0 = *(const float4*)&Bs[cc][tx * 4];
            float4 b1 = *(const float4*)&Bs[cc][64 + tx * 4];
            float ar[2][4] = {{a0.x, a0.y, a0.z, a0.w}, {a1.x, a1.y, a1.z, a1.w}};
            float br[2][4] = {{b0.x, b0.y, b0.z, b0.w}, {b1.x, b1.y, b1.z, b1.w}};
#pragma unroll
            for (int rh = 0; rh < 2; ++rh)
#pragma unroll
                for (int i = 0; i < 4; ++i)
#pragma unroll
                    for (int ch = 0; ch < 2; ++ch)
#pragma unroll
                        for (int j = 0; j < 4; ++j)
                            acc[rh][ch][i][j] = fmaf(ar[rh][i], br[ch][j], acc[rh][ch][i][j]);
        }
        __syncthreads();
    }
    float xr[2][4], xm[2][4];
#pragma unroll
    for (int rh = 0; rh < 2; ++rh)
#pragma unroll
        for (int i = 0; i < 4; ++i) xr[rh][i] = xx[p0 + rowbase + rh * 64 + ty * 4 + i];
#pragma unroll
    for (int ch = 0; ch < 2; ++ch)
#pragma unroll
        for (int j = 0; j < 4; ++j) xm[ch][j] = xx[p0 + colbase + ch * 64 + tx * 4 + j];
    // normal store: pd[r][m] = 2*acc - xx[r] - xx[m]
#pragma unroll
    for (int rh = 0; rh < 2; ++rh)
#pragma unroll
        for (int i = 0; i < 4; ++i) {
            int r = rowbase + rh * 64 + ty * 4 + i;
            float xrv = xr[rh][i];
#pragma unroll
            for (int ch = 0; ch < 2; ++ch) {
                int m = colbase + ch * 64 + tx * 4;
                float4 o;
                o.x = 2.f * acc[rh][ch][i][0] - xrv - xm[ch][0];
                o.y = 2.f * acc[rh][ch][i][1] - xrv - xm[ch][1];
                o.z = 2.f * acc[rh][ch][i][2] - xrv - xm[ch][2];
                o.w = 2.f * acc[rh][ch][i][3] - xrv - xm[ch][3];
                *(float4*)&pd[(size_t)r * NPT + m] = o;
            }
        }
    // mirrored store: pd[m][r] = 2*acc - xx[m] - xx[r]
    if (ti != tj) {
#pragma unroll
        for (int ch = 0; ch < 2; ++ch)
#pragma unroll
            for (int j = 0; j < 4; ++j) {
                int m = colbase + ch * 64 + tx * 4 + j;
                float xmv = xm[ch][j];
#pragma unroll
                for (int rh = 0; rh < 2; ++rh) {
                    float4 o;
                    o.x = 2.f * acc[rh][ch][0][j] - xmv - xr[rh][0];
                    o.y = 2.f * acc[rh][ch][1][j] - xmv - xr[rh][1];
                    o.z = 2.f * acc[rh][ch][2][j] - xmv - xr[rh][2];
                    o.w = 2.f * acc[rh][ch][3][j] - xmv - xr[rh][3];
                    *(float4*)&pd[(size_t)m * NPT + rowbase + rh * 64 + ty * 4] = o;
                }
            }
    }
}

// ---------------- per-lane top-2 scan: 4 independent chains (ILP) ----------------
// chains over contiguous 16-elem groups keep "smallest j wins ties" exact.
template<bool MASKED>
__device__ __forceinline__ void scan4(const float (&v)[64], unsigned long long remM,
                                      float& m1o, float& m2o, int& j1o, int& j2o) {
    float a1[4], a2[4]; int x1[4], x2[4];
#pragma unroll
    for (int c = 0; c < 4; ++c) { a1[c] = NEG_INF; a2[c] = NEG_INF; x1[c] = 0; x2[c] = 0; }
#pragma unroll
    for (int jj = 0; jj < 16; ++jj) {
#pragma unroll
        for (int c = 0; c < 4; ++c) {
            int j = c * 16 + jj;
            float vv = v[j];
            if (MASKED) vv = ((remM >> j) & 1ull) ? NEG_INF : vv;
            bool c1 = vv > a1[c];
            bool c2 = vv > a2[c];
            a2[c] = c1 ? a1[c] : (c2 ? vv : a2[c]);
            x2[c] = c1 ? x1[c] : (c2 ? j : x2[c]);
            a1[c] = c1 ? vv : a1[c];
            x1[c] = c1 ? j : x1[c];
        }
    }
    // merge 4 (top1,top2) pairs; chain c's indices all exceed chain c-1's,
    // so strict > keeps the smaller-j candidate on equal values.
    float m1 = a1[0], m2 = a2[0]; int j1 = x1[0], j2 = x2[0];
#pragma unroll
    for (int c = 1; c < 4; ++c) {
        if (a1[c] > m1) {
            m2 = (a2[c] > m1) ? a2[c] : m1;
            j2 = (a2[c] > m1) ? x2[c] : j1;
            m1 = a1[c]; j1 = x1[c];
        } else {
            j2 = (a1[c] > m2) ? x1[c] : j2;
            m2 = (a1[c] > m2) ? a1[c] : m2;
        }
    }
    m1o = m1; m2o = m2; j1o = j1; j2o = j2;
}

// ---------------- topk core: lazy-rescan extraction, value-only butterfly ----------
// v[64] per lane; global col of v[j] = (j>>2)*256 + lane*4 + (j&3).
__device__ __forceinline__ void topk_core(float (&v)[64], int lane, int b,
                                          int* __restrict__ op) {
    float m1, m2; int j1, j2;
    scan4<false>(v, 0ull, m1, m2, j1, j2);
    bool have2 = true;
    unsigned long long remM = 0ull;
    for (int t = 0; t < 20; ++t) {
        int g1 = ((j1 >> 2) << 8) + (lane << 2) + (j1 & 3);
        float bv = m1;
#pragma unroll
        for (int s = 1; s < 64; s <<= 1) bv = fmaxf(bv, __shfl_xor(bv, s));
        unsigned long long bal = __ballot(m1 == bv);
        int gi;
        if (__popcll(bal) == 1) {
            gi = __shfl(g1, (int)(__ffsll(bal) - 1));   // winner lane's col
        } else {
            // rare equal-value tie: min global col among tied lanes
            int cs = (m1 == bv) ? g1 : 0x7fffffff;
#pragma unroll
            for (int s = 1; s < 64; s <<= 1) cs = min(cs, __shfl_xor(cs, s));
            gi = cs;
        }
        if (lane == 0) op[t] = b * NPT + gi;
        bool needscan = false;
        if (gi == g1) {             // g1 encodes lane -> unique; this lane won
            remM |= 1ull << j1;
            if (have2) { m1 = m2; j1 = j2; have2 = false; }
            else needscan = true;
        }
        if (__any(needscan)) {
            if (needscan) { scan4<true>(v, remM, m1, m2, j1, j2); have2 = true; }
        }
    }
}

// ---------------- top-20 from materialized pd ----------------
__global__ __launch_bounds__(256) void topk20(const float* __restrict__ pd,
                                              int* __restrict__ idxout, int b) {
    int row = blockIdx.x * 4 + (threadIdx.x >> 6);
    int lane = threadIdx.x & 63;
    const float4* prow4 = (const float4*)(pd + (size_t)row * NPT);
    float v[64];
#pragma unroll
    for (int q = 0; q < 16; ++q) {
        float4 t = prow4[q * 64 + lane];
        v[q * 4 + 0] = t.x; v[q * 4 + 1] = t.y;
        v[q * 4 + 2] = t.z; v[q * 4 + 3] = t.w;
    }
    topk_core(v, lane, b, idxout + (size_t)(b * NPT + row) * 20);
}

// ---------------- layer-1 (C=1) fused pd+topk: pd computed inline ----------------
__global__ __launch_bounds__(256) void topk1(const float* __restrict__ X,
                                             const float* __restrict__ xx,
                                             int* __restrict__ idxout) {
    int b = blockIdx.y;
    int row = blockIdx.x * 4 + (threadIdx.x >> 6);
    int lane = threadIdx.x & 63;
    int p0 = b * NPT;
    float xr = X[p0 + row];
    float xxr = xx[p0 + row];
    const float4* xb4 = (const float4*)(X + p0);
    const float4* xxb4 = (const float4*)(xx + p0);
    float v[64];
#pragma unroll
    for (int q = 0; q < 16; ++q) {
        float4 xm = xb4[q * 64 + lane];
        float4 xxm = xxb4[q * 64 + lane];
        v[q * 4 + 0] = (2.f * (xr * xm.x) - xxr) - xxm.x;
        v[q * 4 + 1] = (2.f * (xr * xm.y) - xxr) - xxm.y;
        v[q * 4 + 2] = (2.f * (xr * xm.z) - xxr) - xxm.z;
        v[q * 4 + 3] = (2.f * (xr * xm.w) - xxr) - xxm.w;
    }
    topk_core(v, lane, b, idxout + (size_t)(b * NPT + row) * 20);
}

// ---------------- layer-1 U/T: outer product (C=1, O=64) ----------------
__global__ __launch_bounds__(256) void ut1(const float* __restrict__ X,
                                           const float* __restrict__ w,
                                           float* __restrict__ U,
                                           float* __restrict__ T) {
    int p = blockIdx.x * 4 + (threadIdx.x >> 6);
    int o = threadIdx.x & 63;
    float xv = X[p];
    float wa = w[o * 2];
    float wt = w[o * 2 + 1] - wa;
    U[(size_t)p * 64 + o] = wa * xv;
    T[(size_t)p * 64 + o] = wt * xv;
}

// ---------------- U = wA * X, T = (wB - wA) * X  (point-major out) ----------------
__global__ __launch_bounds__(256) void ut_gemm(const float* __restrict__ X,
                                               const float* __restrict__ w,
                                               float* __restrict__ U,
                                               float* __restrict__ T,
                                               int C, int O) {
    __shared__ float Xs[KC][PAD];
    __shared__ float Wa[KC][PAD];
    __shared__ float Wt[KC][PAD];
    int tid = threadIdx.x;
    int tx = tid & 15;
    int ty = tid >> 4;
    int pbase = blockIdx.x * 64;
    int obase = blockIdx.y * 64;
    int lc = tid & 15;
    int li = tid >> 4;
    float aU[4][4] = {}, aT[4][4] = {};
    for (int c0 = 0; c0 < C; c0 += KC) {
        int c = c0 + lc;
#pragma unroll
        for (int r = 0; r < 4; ++r) {
            int i = li + r * 16;
            Xs[lc][i] = X[(size_t)(pbase + i) * C + c];
            const float* wrow = w + (size_t)(obase + i) * (2 * C);
            float wa = wrow[c];
            Wa[lc][i] = wa;
            Wt[lc][i] = wrow[C + c] - wa;
        }
        __syncthreads();
#pragma unroll
        for (int cc = 0; cc < KC; ++cc) {
            float xv[4], wav[4], wtv[4];
#pragma unroll
            for (int i = 0; i < 4; ++i) xv[i] = Xs[cc][tx * 4 + i];
#pragma unroll
            for (int j = 0; j < 4; ++j) { wav[j] = Wa[cc][ty * 4 + j]; wtv[j] = Wt[cc][ty * 4 + j]; }
#pragma unroll
            for (int j = 0; j < 4; ++j)
#pragma unroll
                for (int i = 0; i < 4; ++i) {
                    aU[j][i] = fmaf(wav[j], xv[i], aU[j][i]);
                    aT[j][i] = fmaf(wtv[j], xv[i], aT[j][i]);
                }
        }
        __syncthreads();
    }
#pragma unroll
    for (int j = 0; j < 4; ++j)
#pragma unroll
        for (int i = 0; i < 4; ++i) {
            size_t p = pbase + tx * 4 + i;
            int o = obase + ty * 4 + j;
            U[p * O + o] = aU[j][i];
            T[p * O + o] = aT[j][i];
        }
}

// ---------------- gather + max-k + BN + LeakyReLU (+ fused xx for next layer) ----
template<int O, bool WXX>
__global__ __launch_bounds__(256) void gather_max4(const float* __restrict__ U,
                                                   const float* __restrict__ T,
                                                   const int* __restrict__ idx,
                                                   const float* __restrict__ g,
                                                   const float* __restrict__ bb,
                                                   const float* __restrict__ rm,
                                                   const float* __restrict__ rv,
                                                   float* __restrict__ Xout,
                                                   float* __restrict__ xxout) {
    constexpr int tpp = O / 4;            // threads per point (16/32/64)
    constexpr int ppb = 256 / tpp;        // points per block
    int lp = threadIdx.x / tpp;
    int o4 = (threadIdx.x % tpp) * 4;
    int p = blockIdx.x * ppb + lp;
    const int* ip = idx + (size_t)p * 20;
    float4 m = {NEG_INF, NEG_INF, NEG_INF, NEG_INF};
#pragma unroll
    for (int k = 0; k < 20; ++k) {
        int j = ip[k];
        float4 u = *(const float4*)&U[(size_t)j * O + o4];
        m.x = fmaxf(m.x, u.x); m.y = fmaxf(m.y, u.y);
        m.z = fmaxf(m.z, u.z); m.w = fmaxf(m.w, u.w);
    }
    float4 t = *(const float4*)&T[(size_t)p * O + o4];
    float4 gg = *(const float4*)&g[o4];
    float4 bv = *(const float4*)&bb[o4];
    float4 rmv = *(const float4*)&rm[o4];
    float4 rvv = *(const float4*)&rv[o4];
    float4 y;
    y.x = (m.x + t.x - rmv.x) * (gg.x / sqrtf(rvv.x + EPS)) + bv.x;
    y.y = (m.y + t.y - rmv.y) * (gg.y / sqrtf(rvv.y + EPS)) + bv.y;
    y.z = (m.z + t.z - rmv.z) * (gg.z / sqrtf(rvv.z + EPS)) + bv.z;
    y.w = (m.w + t.w - rmv.w) * (gg.w / sqrtf(rvv.w + EPS)) + bv.w;
    y.x = y.x > 0.f ? y.x : 0.2f * y.x;
    y.y = y.y > 0.f ? y.y : 0.2f * y.y;
    y.z = y.z > 0.f ? y.z : 0.2f * y.z;
    y.w = y.w > 0.f ? y.w : 0.2f * y.w;
    *(float4*)&Xout[(size_t)p * O + o4] = y;
    if (WXX) {
        float ss = fmaf(y.w, y.w, fmaf(y.z, y.z, fmaf(y.y, y.y, y.x * y.x)));
#pragma unroll
        for (int s = 1; s < tpp; s <<= 1) ss += __shfl_xor(ss, s);
        if ((threadIdx.x & (tpp - 1)) == 0) xxout[p] = ss;
    }
}

// ---------------- head stage 1: 128 o x 128 p tile, 8x8/thread (single buffer) ----
__global__ __launch_bounds__(256) void head_partial(const float* __restrict__ X1,
                                                    const float* __restrict__ X2,
                                                    const float* __restrict__ X3,
                                                    const float* __restrict__ X4,
                                                    const float* __restrict__ w5,
                                                    const float* __restrict__ wreg,
                                                    const float* __restrict__ g,
                                                    const float* __restrict__ bb,
                                                    const float* __restrict__ rm,
                                                    const float* __restrict__ rv,
                                                    float* __restrict__ partial) {
    __shared__ __align__(16) float Ws[KC][PADB];   // A: o rows
    __shared__ __align__(16) float Hs[KC][PADB];   // B: p cols
    __shared__ float red[16][PADB];
    int tid = threadIdx.x;
    int tx = tid & 15;          // p group
    int ty = tid >> 4;          // o group
    int o0 = blockIdx.x * 128;  // 8 o-tiles
    int p0 = blockIdx.y * 128;  // 256 p-tiles
    int sc4 = (tid & 3) * 4;
    int spt = tid >> 2;
    float acc[2][2][4][4] = {}; // [rh(o)][ch(p)][i][j]
    for (int c0 = 0; c0 < 512; c0 += KC) {
        const float* src;
        int coff, Cs;
        if (c0 < 64)       { src = X1; coff = c0;       Cs = 64; }
        else if (c0 < 128) { src = X2; coff = c0 - 64;  Cs = 64; }
        else if (c0 < 256) { src = X3; coff = c0 - 128; Cs = 128; }
        else               { src = X4; coff = c0 - 256; Cs = 256; }
#pragma unroll
        for (int h = 0; h < 2; ++h) {
            int pt = spt + h * 64;
            float4 wv = *(const float4*)&w5[(size_t)(o0 + pt) * 512 + c0 + sc4];
            float4 hv = *(const float4*)&src[(size_t)(p0 + pt) * Cs + coff + sc4];
            Ws[sc4 + 0][pt] = wv.x; Ws[sc4 + 1][pt] = wv.y;
            Ws[sc4 + 2][pt] = wv.z; Ws[sc4 + 3][pt] = wv.w;
            Hs[sc4 + 0][pt] = hv.x; Hs[sc4 + 1][pt] = hv.y;
            Hs[sc4 + 2][pt] = hv.z; Hs[sc4 + 3][pt] = hv.w;
        }
        __syncthreads();
#pragma unroll
        for (int cc = 0; cc < KC; ++cc) {
            float4 a0 = *(const float4*)&Ws[cc][ty * 4];
            float4 a1 = *(const float4*)&Ws[cc][64 + ty * 4];
            float4 b0 = *(const float4*)&Hs[cc][tx * 4];
            float4 b1 = *(const float4*)&Hs[cc][64 + tx * 4];
            float ar[2][4] = {{a0.x, a0.y, a0.z, a0.w}, {a1.x, a1.y, a1.z, a1.w}};
            float br[2][4] = {{b0.x, b0.y, b0.z, b0.w}, {b1.x, b1.y, b1.z, b1.w}};
#pragma unroll
            for (int rh = 0; rh < 2; ++rh)
#pragma unroll
                for (int i = 0; i < 4; ++i)
#pragma unroll
                    for (int ch = 0; ch < 2; ++ch)
#pragma unroll
                        for (int j = 0; j < 4; ++j)
                            acc[rh][ch][i][j] = fmaf(ar[rh][i], br[ch][j], acc[rh][ch][i][j]);
        }
        __syncthreads();
    }
    float pacc[2][4] = {};
#pragma unroll
    for (int rh = 0; rh < 2; ++rh)
#pragma unroll
        for (int i = 0; i < 4; ++i) {
            int o = o0 + rh * 64 + ty * 4 + i;
            float scale = g[o] / sqrtf(rv[o] + EPS);
            float sm = rm[o], sb = bb[o], wr = wreg[o];
#pragma unroll
            for (int ch = 0; ch < 2; ++ch)
#pragma unroll
                for (int j = 0; j < 4; ++j) {
                    float y = (acc[rh][ch][i][j] - sm) * scale + sb;
                    y = y > 0.f ? y : 0.2f * y;
                    pacc[ch][j] = fmaf(wr, y, pacc[ch][j]);
                }
        }
#pragma unroll
    for (int ch = 0; ch < 2; ++ch)
#pragma unroll
        for (int j = 0; j < 4; ++j)
            red[ty][ch * 64 + tx * 4 + j] = pacc[ch][j];
    __syncthreads();
    if (tid < 128) {
        float s = 0.f;
#pragma unroll
        for (int q = 0; q < 16; ++q) s += red[q][tid];
        partial[(size_t)blockIdx.x * PTS + p0 + tid] = s;
    }
}

// ---------------- head stage 2: out[p] = sum over 8 o-tiles ----------------
__global__ __launch_bounds__(256) void head_reduce(const float* __restrict__ partial,
                                                   float* __restrict__ out) {
    int p = blockIdx.x * 256 + threadIdx.x;
    if (p >= PTS) return;
    float s = 0.f;
#pragma unroll
    for (int q = 0; q < 8; ++q) s += partial[(size_t)q * PTS + p];
    out[p] = s;
}

extern "C" void kernel_launch(void* const* d_in, const int* in_sizes, int n_in,
                              void* d_out, int out_size, void* d_ws, size_t ws_size,
                              hipStream_t stream) {
    const float* x    = (const float*)d_in[0];
    const float* w1   = (const float*)d_in[1];
    const float* w2   = (const float*)d_in[2];
    const float* w3   = (const float*)d_in[3];
    const float* w4   = (const float*)d_in[4];
    const float* w5   = (const float*)d_in[5];
    const float* wreg = (const float*)d_in[6];
    const float* bn[5][4];
    for (int t = 0; t < 5; ++t)
        for (int q = 0; q < 4; ++q)
            bn[t][q] = (const float*)d_in[7 + t * 4 + q];
    float* out = (float*)d_out;

    // workspace layout (bytes), peak ~131 MB (proven OK).
    char* ws = (char*)d_ws;
    size_t o_x1  = 0;
    size_t o_x2  = o_x1  + (size_t)PTS * 64 * 4;
    size_t o_x3  = o_x2  + (size_t)PTS * 64 * 4;
    size_t o_x4  = o_x3  + (size_t)PTS * 128 * 4;
    size_t o_idx = o_x4  + (size_t)PTS * 256 * 4;
    size_t o_xx  = o_idx + (size_t)PTS * 20 * 4;
    size_t o_pd  = o_xx  + (size_t)PTS * 4;
    size_t o_u   = o_pd;                            // alias: U over PD slab
    size_t o_t   = o_u   + (size_t)PTS * 256 * 4;

    float* X1 = (float*)(ws + o_x1);
    float* X2 = (float*)(ws + o_x2);
    float* X3 = (float*)(ws + o_x3);
    float* X4 = (float*)(ws + o_x4);
    int*   IDX = (int*)(ws + o_idx);
    float* XX = (float*)(ws + o_xx);
    float* PD = (float*)(ws + o_pd);
    float* U  = (float*)(ws + o_u);
    float* T  = (float*)(ws + o_t);
    float* PART = (float*)(ws + o_idx);   // 8*PTS*4 = 1 MB < IDX slab

    // ---- layer 1 (C=1 -> O=64); emits xx for layer 2 via fused gather ----
    sqnorm<<<PTS / 256, 256, 0, stream>>>(x, XX, 1);
    topk1<<<dim3(NPT / 4, BATCH), 256, 0, stream>>>(x, XX, IDX);
    ut1<<<PTS / 4, 256, 0, stream>>>(x, w1, U, T);
    gather_max4<64, true><<<PTS * 16 / 256, 256, 0, stream>>>(U, T, IDX,
            bn[0][0], bn[0][1], bn[0][2], bn[0][3], X1, XX);

    // ---- layer 2 (C=64 -> O=64) ----
    for (int b = 0; b < BATCH; ++b) {
        pd_sym128<<<528, 256, 0, stream>>>(X1, XX, PD, 64, b);
        topk20<<<NPT / 4, 256, 0, stream>>>(PD, IDX, b);
    }
    ut_gemm<<<dim3(PTS / 64, 1), 256, 0, stream>>>(X1, w2, U, T, 64, 64);
    gather_max4<64, true><<<PTS * 16 / 256, 256, 0, stream>>>(U, T, IDX,
            bn[1][0], bn[1][1], bn[1][2], bn[1][3], X2, XX);

    // ---- layer 3 (C=64 -> O=128) ----
    for (int b = 0; b < BATCH; ++b) {
        pd_sym128<<<528, 256, 0, stream>>>(X2, XX, PD, 64, b);
        topk20<<<NPT / 4, 256, 0, stream>>>(PD, IDX, b);
    }
    ut_gemm<<<dim3(PTS / 64, 2), 256, 0, stream>>>(X2, w3, U, T, 64, 128);
    gather_max4<128, true><<<PTS * 32 / 256, 256, 0, stream>>>(U, T, IDX,
            bn[2][0], bn[2][1], bn[2][2], bn[2][3], X3, XX);

    // ---- layer 4 (C=128 -> O=256); no xx needed downstream ----
    for (int b = 0; b < BATCH; ++b) {
        pd_sym128<<<528, 256, 0, stream>>>(X3, XX, PD, 128, b);
        topk20<<<NPT / 4, 256, 0, stream>>>(PD, IDX, b);
    }
    ut_gemm<<<dim3(PTS / 64, 4), 256, 0, stream>>>(X3, w4, U, T, 128, 256);
    gather_max4<256, false><<<PTS * 64 / 256, 256, 0, stream>>>(U, T, IDX,
            bn[3][0], bn[3][1], bn[3][2], bn[3][3], X4, XX);

    // ---- fused head ----
    head_partial<<<dim3(8, PTS / 128), 256, 0, stream>>>(X1, X2, X3, X4, w5, wreg,
            bn[4][0], bn[4][1], bn[4][2], bn[4][3], PART);
    head_reduce<<<PTS / 256, 256, 0, stream>>>(PART, out);
}

// Round 10
// 2383.974 us; speedup vs baseline: 1.2511x; 1.2511x over previous
//
#include <hip/hip_runtime.h>
#include <math.h>

// DGCNN_Reg: B=8, N=4096, k=20.
// Point-major layouts: X[p][c], U[p][o], T[p][o] with p = b*4096 + n.
// Edge conv factorized: y[o,n,k] = U[idx[n,k]][o] + T[n][o];
// BN+LeakyReLU (scale>0) commutes with max over k.
// R10: full revert to R8 (R9's bundled changes regressed 5.6% and broke the
// absmax bit-canary; unattributable -> revert). New: batch-strided pd/topk
// (bbase + blockIdx.y) with runtime ws_size check -- if workspace fits two
// 64 MB PD slabs (still L3-resident), process batches in pairs, halving
// pd/topk dispatch count. Small-ws path is launch-identical to R8.

constexpr int NPT = 4096;
constexpr int BATCH = 8;
constexpr int PTS = BATCH * NPT;   // 32768
constexpr float EPS = 1e-5f;
#define KC 16
#define PAD 68    // 64-wide tiles: 68 mod 32 = 4 -> conflict-free staging
#define PADB 132  // 128-wide tiles: 132 mod 32 = 4 -> conflict-free staging
#define NEG_INF -3.4e38f

// ---------------- sum of squares per point ----------------
__global__ __launch_bounds__(256) void sqnorm(const float* __restrict__ X,
                                              float* __restrict__ xx, int C) {
    int p = blockIdx.x * 256 + threadIdx.x;
    if (p >= PTS) return;
    float s = 0.f;
    const float* row = X + (size_t)p * C;
    for (int c = 0; c < C; ++c) s = fmaf(row[c], row[c], s);
    xx[p] = s;
}

// ---------------- symmetric pairwise distances, 128x128 tiles, upper triangle ----
// Single-buffer LDS (R8 form). batch = bbase + blockIdx.y; pd slab strided.
__global__ __launch_bounds__(256) void pd_sym128(const float* __restrict__ X,
                                                 const float* __restrict__ xx,
                                                 float* __restrict__ pd0,
                                                 int C, int bbase, size_t pdstride) {
    int b = bbase + blockIdx.y;
    float* pd = pd0 + (size_t)blockIdx.y * pdstride;
    int bid = blockIdx.x;
    int ti = 0, rem = bid;
    while (rem >= 32 - ti) { rem -= 32 - ti; ++ti; }
    int tj = ti + rem;
    int rowbase = ti * 128, colbase = tj * 128;

    __shared__ __align__(16) float As[KC][PADB];
    __shared__ __align__(16) float Bs[KC][PADB];
    int tid = threadIdx.x;
    int tx = tid & 15;          // col group
    int ty = tid >> 4;          // row group
    int p0 = b * NPT;
    int sc4 = (tid & 3) * 4;    // staging channel (float4)
    int spt = tid >> 2;         // staging point 0..63
    float acc[2][2][4][4] = {}; // [rh][ch][i][j]: row 64rh+4ty+i, col 64ch+4tx+j
    for (int c0 = 0; c0 < C; c0 += KC) {
#pragma unroll
        for (int h = 0; h < 2; ++h) {
            int pt = spt + h * 64;
            float4 av = *(const float4*)&X[(size_t)(p0 + rowbase + pt) * C + c0 + sc4];
            float4 bv = *(const float4*)&X[(size_t)(p0 + colbase + pt) * C + c0 + sc4];
            As[sc4 + 0][pt] = av.x; As[sc4 + 1][pt] = av.y;
            As[sc4 + 2][pt] = av.z; As[sc4 + 3][pt] = av.w;
            Bs[sc4 + 0][pt] = bv.x; Bs[sc4 + 1][pt] = bv.y;
            Bs[sc4 + 2][pt] = bv.z; Bs[sc4 + 3][pt] = bv.w;
        }
        __syncthreads();
#pragma unroll
        for (int cc = 0; cc < KC; ++cc) {
            float4 a0 = *(const float4*)&As[cc][ty * 4];
            float4 a1 = *(const float4*)&As[cc][64 + ty * 4];
            float4 b0 = *(const float4*)&Bs[cc][tx * 4];
            float4 b1 = *(const float4*)&Bs[cc][64 + tx * 4];
            float ar[2][4] = {{a0.x, a0.y, a0.z, a0.w}, {a1.x, a1.y, a1.z, a1.w}};
            float br[2][4] = {{b0.x, b0.y, b0.z, b0.w}, {b1.x, b1.y, b1.z, b1.w}};
#pragma unroll
            for (int rh = 0; rh < 2; ++rh)
#pragma unroll
                for (int i = 0; i < 4; ++i)
#pragma unroll
                    for (int ch = 0; ch < 2; ++ch)
#pragma unroll
                        for (int j = 0; j < 4; ++j)
                            acc[rh][ch][i][j] = fmaf(ar[rh][i], br[ch][j], acc[rh][ch][i][j]);
        }
        __syncthreads();
    }
    float xr[2][4], xm[2][4];
#pragma unroll
    for (int rh = 0; rh < 2; ++rh)
#pragma unroll
        for (int i = 0; i < 4; ++i) xr[rh][i] = xx[p0 + rowbase + rh * 64 + ty * 4 + i];
#pragma unroll
    for (int ch = 0; ch < 2; ++ch)
#pragma unroll
        for (int j = 0; j < 4; ++j) xm[ch][j] = xx[p0 + colbase + ch * 64 + tx * 4 + j];
    // normal store: pd[r][m] = 2*acc - xx[r] - xx[m]
#pragma unroll
    for (int rh = 0; rh < 2; ++rh)
#pragma unroll
        for (int i = 0; i < 4; ++i) {
            int r = rowbase + rh * 64 + ty * 4 + i;
            float xrv = xr[rh][i];
#pragma unroll
            for (int ch = 0; ch < 2; ++ch) {
                int m = colbase + ch * 64 + tx * 4;
                float4 o;
                o.x = 2.f * acc[rh][ch][i][0] - xrv - xm[ch][0];
                o.y = 2.f * acc[rh][ch][i][1] - xrv - xm[ch][1];
                o.z = 2.f * acc[rh][ch][i][2] - xrv - xm[ch][2];
                o.w = 2.f * acc[rh][ch][i][3] - xrv - xm[ch][3];
                *(float4*)&pd[(size_t)r * NPT + m] = o;
            }
        }
    // mirrored store: pd[m][r] = 2*acc - xx[m] - xx[r]
    if (ti != tj) {
#pragma unroll
        for (int ch = 0; ch < 2; ++ch)
#pragma unroll
            for (int j = 0; j < 4; ++j) {
                int m = colbase + ch * 64 + tx * 4 + j;
                float xmv = xm[ch][j];
#pragma unroll
                for (int rh = 0; rh < 2; ++rh) {
                    float4 o;
                    o.x = 2.f * acc[rh][ch][0][j] - xmv - xr[rh][0];
                    o.y = 2.f * acc[rh][ch][1][j] - xmv - xr[rh][1];
                    o.z = 2.f * acc[rh][ch][2][j] - xmv - xr[rh][2];
                    o.w = 2.f * acc[rh][ch][3][j] - xmv - xr[rh][3];
                    *(float4*)&pd[(size_t)m * NPT + rowbase + rh * 64 + ty * 4] = o;
                }
            }
    }
}

// ---------------- shared topk core: per-lane top-2 + lazy rescan (R8 form) ------
// v[64] per lane; global col of v[j] = (j>>2)*256 + lane*4 + (j&3).
__device__ __forceinline__ void topk_core(float (&v)[64], int lane, int b,
                                          int* __restrict__ op) {
    float m1 = NEG_INF, m2 = NEG_INF;
    int j1 = 0, j2 = 0;
#pragma unroll
    for (int j = 0; j < 64; ++j) {
        float vv = v[j];
        bool c1 = vv > m1;          // strict > : earlier (smaller) j wins ties
        bool c2 = vv > m2;
        m2 = c1 ? m1 : (c2 ? vv : m2);
        j2 = c1 ? j1 : (c2 ? j : j2);
        m1 = c1 ? vv : m1;
        j1 = c1 ? j : j1;
    }
    bool have2 = true;
    unsigned long long remM = 0ull;
    for (int t = 0; t < 20; ++t) {
        int g1 = ((j1 >> 2) << 8) + (lane << 2) + (j1 & 3);
        float bv = m1; int gi = g1;
#pragma unroll
        for (int s = 1; s < 64; s <<= 1) {
            float ov = __shfl_xor(bv, s);
            int og = __shfl_xor(gi, s);
            if (ov > bv || (ov == bv && og < gi)) { bv = ov; gi = og; }
        }
        if (lane == 0) op[t] = b * NPT + gi;
        bool needscan = false;
        if (gi == g1) {             // g1 encodes lane -> unique; this lane won
            remM |= 1ull << j1;
            if (have2) { m1 = m2; j1 = j2; have2 = false; }
            else needscan = true;
        }
        if (__any(needscan)) {
            if (needscan) {
                m1 = NEG_INF; m2 = NEG_INF; j1 = 0; j2 = 0;
#pragma unroll
                for (int j = 0; j < 64; ++j) {
                    bool alive = !((remM >> j) & 1ull);
                    float vv = alive ? v[j] : NEG_INF;
                    bool c1 = vv > m1;
                    bool c2 = vv > m2;
                    m2 = c1 ? m1 : (c2 ? vv : m2);
                    j2 = c1 ? j1 : (c2 ? j : j2);
                    m1 = c1 ? vv : m1;
                    j1 = c1 ? j : j1;
                }
                have2 = true;
            }
        }
    }
}

// ---------------- top-20 from materialized pd (batch-strided) ----------------
__global__ __launch_bounds__(256) void topk20(const float* __restrict__ pd0,
                                              int* __restrict__ idxout,
                                              int bbase, size_t pdstride) {
    int b = bbase + blockIdx.y;
    const float* pd = pd0 + (size_t)blockIdx.y * pdstride;
    int row = blockIdx.x * 4 + (threadIdx.x >> 6);
    int lane = threadIdx.x & 63;
    const float4* prow4 = (const float4*)(pd + (size_t)row * NPT);
    float v[64];
#pragma unroll
    for (int q = 0; q < 16; ++q) {
        float4 t = prow4[q * 64 + lane];
        v[q * 4 + 0] = t.x; v[q * 4 + 1] = t.y;
        v[q * 4 + 2] = t.z; v[q * 4 + 3] = t.w;
    }
    topk_core(v, lane, b, idxout + (size_t)(b * NPT + row) * 20);
}

// ---------------- layer-1 (C=1) fused pd+topk: pd computed inline ----------------
__global__ __launch_bounds__(256) void topk1(const float* __restrict__ X,
                                             const float* __restrict__ xx,
                                             int* __restrict__ idxout) {
    int b = blockIdx.y;
    int row = blockIdx.x * 4 + (threadIdx.x >> 6);
    int lane = threadIdx.x & 63;
    int p0 = b * NPT;
    float xr = X[p0 + row];
    float xxr = xx[p0 + row];
    const float4* xb4 = (const float4*)(X + p0);
    const float4* xxb4 = (const float4*)(xx + p0);
    float v[64];
#pragma unroll
    for (int q = 0; q < 16; ++q) {
        float4 xm = xb4[q * 64 + lane];
        float4 xxm = xxb4[q * 64 + lane];
        v[q * 4 + 0] = (2.f * (xr * xm.x) - xxr) - xxm.x;
        v[q * 4 + 1] = (2.f * (xr * xm.y) - xxr) - xxm.y;
        v[q * 4 + 2] = (2.f * (xr * xm.z) - xxr) - xxm.z;
        v[q * 4 + 3] = (2.f * (xr * xm.w) - xxr) - xxm.w;
    }
    topk_core(v, lane, b, idxout + (size_t)(b * NPT + row) * 20);
}

// ---------------- layer-1 U/T: outer product (C=1, O=64) ----------------
__global__ __launch_bounds__(256) void ut1(const float* __restrict__ X,
                                           const float* __restrict__ w,
                                           float* __restrict__ U,
                                           float* __restrict__ T) {
    int p = blockIdx.x * 4 + (threadIdx.x >> 6);
    int o = threadIdx.x & 63;
    float xv = X[p];
    float wa = w[o * 2];
    float wt = w[o * 2 + 1] - wa;
    U[(size_t)p * 64 + o] = wa * xv;
    T[(size_t)p * 64 + o] = wt * xv;
}

// ---------------- U = wA * X, T = (wB - wA) * X  (point-major out) ----------------
__global__ __launch_bounds__(256) void ut_gemm(const float* __restrict__ X,
                                               const float* __restrict__ w,
                                               float* __restrict__ U,
                                               float* __restrict__ T,
                                               int C, int O) {
    __shared__ float Xs[KC][PAD];
    __shared__ float Wa[KC][PAD];
    __shared__ float Wt[KC][PAD];
    int tid = threadIdx.x;
    int tx = tid & 15;
    int ty = tid >> 4;
    int pbase = blockIdx.x * 64;
    int obase = blockIdx.y * 64;
    int lc = tid & 15;
    int li = tid >> 4;
    float aU[4][4] = {}, aT[4][4] = {};
    for (int c0 = 0; c0 < C; c0 += KC) {
        int c = c0 + lc;
#pragma unroll
        for (int r = 0; r < 4; ++r) {
            int i = li + r * 16;
            Xs[lc][i] = X[(size_t)(pbase + i) * C + c];
            const float* wrow = w + (size_t)(obase + i) * (2 * C);
            float wa = wrow[c];
            Wa[lc][i] = wa;
            Wt[lc][i] = wrow[C + c] - wa;
        }
        __syncthreads();
#pragma unroll
        for (int cc = 0; cc < KC; ++cc) {
            float xv[4], wav[4], wtv[4];
#pragma unroll
            for (int i = 0; i < 4; ++i) xv[i] = Xs[cc][tx * 4 + i];
#pragma unroll
            for (int j = 0; j < 4; ++j) { wav[j] = Wa[cc][ty * 4 + j]; wtv[j] = Wt[cc][ty * 4 + j]; }
#pragma unroll
            for (int j = 0; j < 4; ++j)
#pragma unroll
                for (int i = 0; i < 4; ++i) {
                    aU[j][i] = fmaf(wav[j], xv[i], aU[j][i]);
                    aT[j][i] = fmaf(wtv[j], xv[i], aT[j][i]);
                }
        }
        __syncthreads();
    }
#pragma unroll
    for (int j = 0; j < 4; ++j)
#pragma unroll
        for (int i = 0; i < 4; ++i) {
            size_t p = pbase + tx * 4 + i;
            int o = obase + ty * 4 + j;
            U[p * O + o] = aU[j][i];
            T[p * O + o] = aT[j][i];
        }
}

// ---------------- gather neighbors, max over k, BN + LeakyReLU (float4 over o) ----
__global__ __launch_bounds__(256) void gather_max4(const float* __restrict__ U,
                                                   const float* __restrict__ T,
                                                   const int* __restrict__ idx,
                                                   const float* __restrict__ g,
                                                   const float* __restrict__ bb,
                                                   const float* __restrict__ rm,
                                                   const float* __restrict__ rv,
                                                   float* __restrict__ Xout, int O) {
    int tpp = O / 4;                      // threads per point
    int ppb = 256 / tpp;                  // points per block
    int lp = threadIdx.x / tpp;
    int o4 = (threadIdx.x % tpp) * 4;
    int p = blockIdx.x * ppb + lp;
    const int* ip = idx + (size_t)p * 20;
    float4 m = {NEG_INF, NEG_INF, NEG_INF, NEG_INF};
#pragma unroll
    for (int k = 0; k < 20; ++k) {
        int j = ip[k];
        float4 u = *(const float4*)&U[(size_t)j * O + o4];
        m.x = fmaxf(m.x, u.x); m.y = fmaxf(m.y, u.y);
        m.z = fmaxf(m.z, u.z); m.w = fmaxf(m.w, u.w);
    }
    float4 t = *(const float4*)&T[(size_t)p * O + o4];
    float4 gg = *(const float4*)&g[o4];
    float4 bv = *(const float4*)&bb[o4];
    float4 rmv = *(const float4*)&rm[o4];
    float4 rvv = *(const float4*)&rv[o4];
    float4 y;
    y.x = (m.x + t.x - rmv.x) * (gg.x / sqrtf(rvv.x + EPS)) + bv.x;
    y.y = (m.y + t.y - rmv.y) * (gg.y / sqrtf(rvv.y + EPS)) + bv.y;
    y.z = (m.z + t.z - rmv.z) * (gg.z / sqrtf(rvv.z + EPS)) + bv.z;
    y.w = (m.w + t.w - rmv.w) * (gg.w / sqrtf(rvv.w + EPS)) + bv.w;
    y.x = y.x > 0.f ? y.x : 0.2f * y.x;
    y.y = y.y > 0.f ? y.y : 0.2f * y.y;
    y.z = y.z > 0.f ? y.z : 0.2f * y.z;
    y.w = y.w > 0.f ? y.w : 0.2f * y.w;
    *(float4*)&Xout[(size_t)p * O + o4] = y;
}

// ---------------- head stage 1: 128 o x 128 p tile, 8x8/thread (single buffer) ----
__global__ __launch_bounds__(256) void head_partial(const float* __restrict__ X1,
                                                    const float* __restrict__ X2,
                                                    const float* __restrict__ X3,
                                                    const float* __restrict__ X4,
                                                    const float* __restrict__ w5,
                                                    const float* __restrict__ wreg,
                                                    const float* __restrict__ g,
                                                    const float* __restrict__ bb,
                                                    const float* __restrict__ rm,
                                                    const float* __restrict__ rv,
                                                    float* __restrict__ partial) {
    __shared__ __align__(16) float Ws[KC][PADB];   // A: o rows
    __shared__ __align__(16) float Hs[KC][PADB];   // B: p cols
    __shared__ float red[16][PADB];
    int tid = threadIdx.x;
    int tx = tid & 15;          // p group
    int ty = tid >> 4;          // o group
    int o0 = blockIdx.x * 128;  // 8 o-tiles
    int p0 = blockIdx.y * 128;  // 256 p-tiles
    int sc4 = (tid & 3) * 4;
    int spt = tid >> 2;
    float acc[2][2][4][4] = {}; // [rh(o)][ch(p)][i][j]
    for (int c0 = 0; c0 < 512; c0 += KC) {
        const float* src;
        int coff, Cs;
        if (c0 < 64)       { src = X1; coff = c0;       Cs = 64; }
        else if (c0 < 128) { src = X2; coff = c0 - 64;  Cs = 64; }
        else if (c0 < 256) { src = X3; coff = c0 - 128; Cs = 128; }
        else               { src = X4; coff = c0 - 256; Cs = 256; }
#pragma unroll
        for (int h = 0; h < 2; ++h) {
            int pt = spt + h * 64;
            float4 wv = *(const float4*)&w5[(size_t)(o0 + pt) * 512 + c0 + sc4];
            float4 hv = *(const float4*)&src[(size_t)(p0 + pt) * Cs + coff + sc4];
            Ws[sc4 + 0][pt] = wv.x; Ws[sc4 + 1][pt] = wv.y;
            Ws[sc4 + 2][pt] = wv.z; Ws[sc4 + 3][pt] = wv.w;
            Hs[sc4 + 0][pt] = hv.x; Hs[sc4 + 1][pt] = hv.y;
            Hs[sc4 + 2][pt] = hv.z; Hs[sc4 + 3][pt] = hv.w;
        }
        __syncthreads();
#pragma unroll
        for (int cc = 0; cc < KC; ++cc) {
            float4 a0 = *(const float4*)&Ws[cc][ty * 4];
            float4 a1 = *(const float4*)&Ws[cc][64 + ty * 4];
            float4 b0 = *(const float4*)&Hs[cc][tx * 4];
            float4 b1 = *(const float4*)&Hs[cc][64 + tx * 4];
            float ar[2][4] = {{a0.x, a0.y, a0.z, a0.w}, {a1.x, a1.y, a1.z, a1.w}};
            float br[2][4] = {{b0.x, b0.y, b0.z, b0.w}, {b1.x, b1.y, b1.z, b1.w}};
#pragma unroll
            for (int rh = 0; rh < 2; ++rh)
#pragma unroll
                for (int i = 0; i < 4; ++i)
#pragma unroll
                    for (int ch = 0; ch < 2; ++ch)
#pragma unroll
                        for (int j = 0; j < 4; ++j)
                            acc[rh][ch][i][j] = fmaf(ar[rh][i], br[ch][j], acc[rh][ch][i][j]);
        }
        __syncthreads();
    }
    float pacc[2][4] = {};
#pragma unroll
    for (int rh = 0; rh < 2; ++rh)
#pragma unroll
        for (int i = 0; i < 4; ++i) {
            int o = o0 + rh * 64 + ty * 4 + i;
            float scale = g[o] / sqrtf(rv[o] + EPS);
            float sm = rm[o], sb = bb[o], wr = wreg[o];
#pragma unroll
            for (int ch = 0; ch < 2; ++ch)
#pragma unroll
                for (int j = 0; j < 4; ++j) {
                    float y = (acc[rh][ch][i][j] - sm) * scale + sb;
                    y = y > 0.f ? y : 0.2f * y;
                    pacc[ch][j] = fmaf(wr, y, pacc[ch][j]);
                }
        }
#pragma unroll
    for (int ch = 0; ch < 2; ++ch)
#pragma unroll
        for (int j = 0; j < 4; ++j)
            red[ty][ch * 64 + tx * 4 + j] = pacc[ch][j];
    __syncthreads();
    if (tid < 128) {
        float s = 0.f;
#pragma unroll
        for (int q = 0; q < 16; ++q) s += red[q][tid];
        partial[(size_t)blockIdx.x * PTS + p0 + tid] = s;
    }
}

// ---------------- head stage 2: out[p] = sum over 8 o-tiles ----------------
__global__ __launch_bounds__(256) void head_reduce(const float* __restrict__ partial,
                                                   float* __restrict__ out) {
    int p = blockIdx.x * 256 + threadIdx.x;
    if (p >= PTS) return;
    float s = 0.f;
#pragma unroll
    for (int q = 0; q < 8; ++q) s += partial[(size_t)q * PTS + p];
    out[p] = s;
}

extern "C" void kernel_launch(void* const* d_in, const int* in_sizes, int n_in,
                              void* d_out, int out_size, void* d_ws, size_t ws_size,
                              hipStream_t stream) {
    const float* x    = (const float*)d_in[0];
    const float* w1   = (const float*)d_in[1];
    const float* w2   = (const float*)d_in[2];
    const float* w3   = (const float*)d_in[3];
    const float* w4   = (const float*)d_in[4];
    const float* w5   = (const float*)d_in[5];
    const float* wreg = (const float*)d_in[6];
    const float* bn[5][4];
    for (int t = 0; t < 5; ++t)
        for (int q = 0; q < 4; ++q)
            bn[t][q] = (const float*)d_in[7 + t * 4 + q];
    float* out = (float*)d_out;

    // workspace layout (bytes). Base footprint ~131 MB (proven OK). If ws_size
    // also fits a SECOND 64 MB PD slab (~195 MB), process batches in pairs.
    char* ws = (char*)d_ws;
    size_t o_x1  = 0;
    size_t o_x2  = o_x1  + (size_t)PTS * 64 * 4;
    size_t o_x3  = o_x2  + (size_t)PTS * 64 * 4;
    size_t o_x4  = o_x3  + (size_t)PTS * 128 * 4;
    size_t o_idx = o_x4  + (size_t)PTS * 256 * 4;
    size_t o_xx  = o_idx + (size_t)PTS * 20 * 4;
    size_t o_pd  = o_xx  + (size_t)PTS * 4;
    size_t o_u   = o_pd;                            // alias: U over PD slab
    size_t o_t   = o_u   + (size_t)PTS * 256 * 4;
    size_t pdslab = (size_t)NPT * NPT * 4;          // 64 MB

    float* X1 = (float*)(ws + o_x1);
    float* X2 = (float*)(ws + o_x2);
    float* X3 = (float*)(ws + o_x3);
    float* X4 = (float*)(ws + o_x4);
    int*   IDX = (int*)(ws + o_idx);
    float* XX = (float*)(ws + o_xx);
    float* PD = (float*)(ws + o_pd);
    float* U  = (float*)(ws + o_u);
    float* T  = (float*)(ws + o_t);
    float* PART = (float*)(ws + o_idx);   // 8*PTS*4 = 1 MB < IDX slab

    // pair-batching if workspace allows two PD slabs (both L3-resident)
    const bool pair = ws_size >= o_pd + 2 * pdslab;
    const int bstep = pair ? 2 : 1;
    const size_t pdstride = pair ? (pdslab / 4) * 0 + (size_t)NPT * NPT : 0;
    // (pdstride is in floats for pointer math below)

    auto knn_layer = [&](const float* Xin, int C) {
        for (int b = 0; b < BATCH; b += bstep) {
            pd_sym128<<<dim3(528, bstep), 256, 0, stream>>>(Xin, XX, PD, C, b,
                                                            pair ? (size_t)NPT * NPT : 0);
            topk20<<<dim3(NPT / 4, bstep), 256, 0, stream>>>(PD, IDX, b,
                                                             pair ? (size_t)NPT * NPT : 0);
        }
    };

    // ---- layer 1 (C=1 -> O=64) ----
    sqnorm<<<PTS / 256, 256, 0, stream>>>(x, XX, 1);
    topk1<<<dim3(NPT / 4, BATCH), 256, 0, stream>>>(x, XX, IDX);
    ut1<<<PTS / 4, 256, 0, stream>>>(x, w1, U, T);
    gather_max4<<<PTS * 16 / 256, 256, 0, stream>>>(U, T, IDX,
            bn[0][0], bn[0][1], bn[0][2], bn[0][3], X1, 64);

    // ---- layer 2 (C=64 -> O=64) ----
    sqnorm<<<PTS / 256, 256, 0, stream>>>(X1, XX, 64);
    knn_layer(X1, 64);
    ut_gemm<<<dim3(PTS / 64, 1), 256, 0, stream>>>(X1, w2, U, T, 64, 64);
    gather_max4<<<PTS * 16 / 256, 256, 0, stream>>>(U, T, IDX,
            bn[1][0], bn[1][1], bn[1][2], bn[1][3], X2, 64);

    // ---- layer 3 (C=64 -> O=128) ----
    sqnorm<<<PTS / 256, 256, 0, stream>>>(X2, XX, 64);
    knn_layer(X2, 64);
    ut_gemm<<<dim3(PTS / 64, 2), 256, 0, stream>>>(X2, w3, U, T, 64, 128);
    gather_max4<<<PTS * 32 / 256, 256, 0, stream>>>(U, T, IDX,
            bn[2][0], bn[2][1], bn[2][2], bn[2][3], X3, 128);

    // ---- layer 4 (C=128 -> O=256) ----
    sqnorm<<<PTS / 256, 256, 0, stream>>>(X3, XX, 128);
    knn_layer(X3, 128);
    ut_gemm<<<dim3(PTS / 64, 4), 256, 0, stream>>>(X3, w4, U, T, 128, 256);
    gather_max4<<<PTS * 64 / 256, 256, 0, stream>>>(U, T, IDX,
            bn[3][0], bn[3][1], bn[3][2], bn[3][3], X4, 256);

    // ---- fused head ----
    head_partial<<<dim3(8, PTS / 128), 256, 0, stream>>>(X1, X2, X3, X4, w5, wreg,
            bn[4][0], bn[4][1], bn[4][2], bn[4][3], PART);
    head_reduce<<<PTS / 256, 256, 0, stream>>>(PART, out);
}